// Round 3
// baseline (603.667 us; speedup 1.0000x reference)
//
#include <hip/hip_runtime.h>
#include <math.h>

#define HWp 16384
#define CH 64
#define KC 8
#define WSTRIDE 136

typedef __attribute__((ext_vector_type(8))) short bf16x8;
typedef __attribute__((ext_vector_type(4))) float f32x4;

#define MFMA(a, b, c) __builtin_amdgcn_mfma_f32_16x16x32_bf16(a, b, c, 0, 0, 0)

__device__ __forceinline__ short f2bf(float f) {
  unsigned u = __float_as_uint(f);
  u += 0x7FFFu + ((u >> 16) & 1u);
  return (short)(u >> 16);
}
__device__ __forceinline__ float bf2f(short s) {
  return __uint_as_float(((unsigned)(unsigned short)s) << 16);
}
__device__ __forceinline__ bf16x8 ldB(const short* __restrict__ W, int nrow, int c0) {
  return *(const bf16x8*)(W + nrow * WSTRIDE + c0);
}
__device__ __forceinline__ bf16x8 cvt8(const float* r) {
  bf16x8 a;
#pragma unroll
  for (int j = 0; j < 8; ++j) a[j] = f2bf(r[j]);
  return a;
}

// Fold MHA in-projection into q/k/v linears; store W^T[e][c] bf16 (stride 136) + biases fp32.
__global__ void setup_weights(const float* __restrict__ q1w, const float* __restrict__ q1b,
                              const float* __restrict__ k1w, const float* __restrict__ k1b,
                              const float* __restrict__ v1w, const float* __restrict__ v1b,
                              const float* __restrict__ q2w, const float* __restrict__ q2b,
                              const float* __restrict__ k2w, const float* __restrict__ k2b,
                              const float* __restrict__ v2w, const float* __restrict__ v2b,
                              const float* __restrict__ ipw, const float* __restrict__ ipb,
                              const float* __restrict__ ow, short* __restrict__ Wt,
                              float* __restrict__ Bc) {
  int id = blockIdx.y;
  int idx = blockIdx.x * 256 + threadIdx.x;
  if (id == 6) {
    if (idx < 4096) {
      int e = idx >> 6, d = idx & 63;
      Wt[(6 * 64 + e) * WSTRIDE + d] = f2bf(ow[e * 64 + d]);
    }
    return;
  }
  const float* lw; const float* lb; int K, off;
  switch (id) {
    case 0:  lw = q1w; lb = q1b; K = 66;  off = 0;   break;
    case 1:  lw = k1w; lb = k1b; K = 66;  off = 64;  break;
    case 2:  lw = v1w; lb = v1b; K = 64;  off = 128; break;
    case 3:  lw = q2w; lb = q2b; K = 130; off = 0;   break;
    case 4:  lw = k2w; lb = k2b; K = 130; off = 64;  break;
    default: lw = v2w; lb = v2b; K = 128; off = 128; break;
  }
  if (idx < K * 64) {
    int c = idx >> 6, e = idx & 63;
    float s = 0.f;
    for (int f = 0; f < 64; ++f) s += ipw[(off + e) * 64 + f] * lw[f * K + c];
    Wt[(id * 64 + e) * WSTRIDE + c] = f2bf(s);
  } else if (idx < K * 64 + 64) {
    int e = idx - K * 64;
    float s = ipb[off + e];
    for (int f = 0; f < 64; ++f) s += ipw[(off + e) * 64 + f] * lb[f];
    Bc[id * 64 + e] = s;
  }
}

// ---------------- Stage 1 ----------------
__global__ __launch_bounds__(256) void stage1(const float* __restrict__ HFs,
                                              const float* __restrict__ HFc,
                                              const float* __restrict__ Zc,
                                              const short* __restrict__ Wt,
                                              const float* __restrict__ Bc,
                                              const float* __restrict__ outb,
                                              short* __restrict__ zb) {
  const int t = threadIdx.x, wv = t >> 6, l = t & 63;
  const int tile = blockIdx.x, b = tile >> 11, p0 = (tile & 2047) << 3;
  const int m0 = p0 << 3, k0 = m0 >> 14, poff = m0 & (HWp - 1);

  __shared__ float AO[8 * 68];

  const int am = l & 15, kg = l >> 4;
  const int row0 = wv << 4;
  const int c0a = kg * 8;
  const int rowK = row0 + am;
  const int pq = p0 + 2 * wv + (am >> 3);  // A-row pixel for Q fragment

  const short* Wq = Wt;
  const short* Wk = Wt + 64 * WSTRIDE;
  const short* Wv = Wt + 2 * 64 * WSTRIDE;
  const short* Wo = Wt + 6 * 64 * WSTRIDE;
  const float* BQ = Bc;
  const float* BK = Bc + 64;
  const float* BV = Bc + 128;

  const float* baseKc = HFc + ((size_t)(b * KC + k0) * CH) * HWp + poff;
  const float* baseZc = Zc + ((size_t)(b * KC + k0) * CH) * HWp + poff;
  const float* baseQ = HFs + (size_t)b * CH * HWp;
  const float inv127 = 1.f / 127.f;

  // ---- prefetch all global A-data (raw fp32) ----
  float rK[16], rQ[16], rV[16];
#pragma unroll
  for (int ks = 0; ks < 2; ++ks)
#pragma unroll
    for (int j = 0; j < 8; ++j)
      rK[ks * 8 + j] = baseKc[(size_t)(ks * 32 + c0a + j) * HWp + rowK];
#pragma unroll
  for (int ks = 0; ks < 2; ++ks)
#pragma unroll
    for (int j = 0; j < 8; ++j)
      rQ[ks * 8 + j] = baseQ[(size_t)(ks * 32 + c0a + j) * HWp + pq];
#pragma unroll
  for (int ks = 0; ks < 2; ++ks)
#pragma unroll
    for (int j = 0; j < 8; ++j)
      rV[ks * 8 + j] = baseZc[(size_t)(ks * 32 + c0a + j) * HWp + rowK];

  // ---- K & Q GEMMs (bias + coords folded into acc init) ----
  const int pqd = p0 + 2 * wv + (kg >> 1);  // D-row pixel
  const float qi = (float)(pqd >> 7) * inv127, qj = (float)(pqd & 127) * inv127;
  f32x4 kacc[4], qacc[4];
#pragma unroll
  for (int ct = 0; ct < 4; ++ct) {
    int col = ct * 16 + am;
    float bk = BK[col], wi = bf2f(Wk[col * WSTRIDE + 64]), wj = bf2f(Wk[col * WSTRIDE + 65]);
#pragma unroll
    for (int r = 0; r < 4; ++r) {
      int pp = poff + row0 + kg * 4 + r;
      kacc[ct][r] = bk + (float)(pp >> 7) * inv127 * wi + (float)(pp & 127) * inv127 * wj;
    }
    float bq = BQ[col] + qi * bf2f(Wq[col * WSTRIDE + 64]) + qj * bf2f(Wq[col * WSTRIDE + 65]);
#pragma unroll
    for (int r = 0; r < 4; ++r) qacc[ct][r] = bq;
  }
#pragma unroll
  for (int ks = 0; ks < 2; ++ks) {
    int c0 = ks * 32 + c0a;
    bf16x8 aK = cvt8(rK + ks * 8), aQ = cvt8(rQ + ks * 8);
#pragma unroll
    for (int ct = 0; ct < 4; ++ct) {
      kacc[ct] = MFMA(aK, ldB(Wk, ct * 16 + am, c0), kacc[ct]);
      qacc[ct] = MFMA(aQ, ldB(Wq, ct * 16 + am, c0), qacc[ct]);
    }
  }

  // ---- scores in-register: reduce over 16 n-lanes ----
  float sc[4][4];
#pragma unroll
  for (int ct = 0; ct < 4; ++ct)
#pragma unroll
    for (int r = 0; r < 4; ++r) sc[ct][r] = kacc[ct][r] * qacc[ct][0];
#pragma unroll
  for (int m = 1; m < 16; m <<= 1)
#pragma unroll
    for (int ct = 0; ct < 4; ++ct)
#pragma unroll
      for (int r = 0; r < 4; ++r) sc[ct][r] += __shfl_xor(sc[ct][r], m);

  float aw[4][4];
#pragma unroll
  for (int ct = 0; ct < 4; ++ct) {
    float so[4];
#pragma unroll
    for (int r = 0; r < 4; ++r) { sc[ct][r] *= 0.25f; so[r] = __shfl_xor(sc[ct][r], 16); }
    float mx = fmaxf(fmaxf(fmaxf(sc[ct][0], sc[ct][1]), fmaxf(sc[ct][2], sc[ct][3])),
                     fmaxf(fmaxf(so[0], so[1]), fmaxf(so[2], so[3])));
    float e[4], s = 0.f;
#pragma unroll
    for (int r = 0; r < 4; ++r) { e[r] = __expf(sc[ct][r] - mx); s += e[r]; }
#pragma unroll
    for (int r = 0; r < 4; ++r) s += __expf(so[r] - mx);
    float inv = 1.0f / s;
#pragma unroll
    for (int r = 0; r < 4; ++r) aw[ct][r] = e[r] * inv;
  }

  // ---- V GEMM ----
  f32x4 vacc[4];
#pragma unroll
  for (int ct = 0; ct < 4; ++ct) {
    float bv = BV[ct * 16 + am];
#pragma unroll
    for (int r = 0; r < 4; ++r) vacc[ct][r] = bv;
  }
#pragma unroll
  for (int ks = 0; ks < 2; ++ks) {
    int c0 = ks * 32 + c0a;
    bf16x8 aV = cvt8(rV + ks * 8);
#pragma unroll
    for (int ct = 0; ct < 4; ++ct) vacc[ct] = MFMA(aV, ldB(Wv, ct * 16 + am, c0), vacc[ct]);
  }

  // ---- attn @ V in-register ----
#pragma unroll
  for (int ct = 0; ct < 4; ++ct) {
    float po = aw[ct][0] * vacc[ct][0] + aw[ct][1] * vacc[ct][1] +
               aw[ct][2] * vacc[ct][2] + aw[ct][3] * vacc[ct][3];
    po += __shfl_xor(po, 16);
    if ((kg & 1) == 0) AO[(2 * wv + (kg >> 1)) * 68 + ct * 16 + am] = po;
  }
  __syncthreads();

  // ---- out-projection -> z (bf16) ----
  {
    int colo = wv * 16 + am;
    f32x4 oacc;
    float bo = outb[colo];
#pragma unroll
    for (int r = 0; r < 4; ++r) oacc[r] = bo;
#pragma unroll
    for (int ks = 0; ks < 2; ++ks) {
      int c0 = ks * 32 + c0a;
      bf16x8 a;
#pragma unroll
      for (int j = 0; j < 8; ++j) a[j] = f2bf(AO[(am & 7) * 68 + c0 + j]);
      oacc = MFMA(a, ldB(Wo, colo, c0), oacc);
    }
#pragma unroll
    for (int r = 0; r < 4; ++r) {
      int m = kg * 4 + r;
      if (m < 8) zb[((size_t)(b * HWp + p0 + m)) * 64 + colo] = f2bf(oacc[r]);
    }
  }
}

// ---------------- Stage 2 ----------------
__global__ __launch_bounds__(256) void stage2(const float* __restrict__ HFs,
                                              const float* __restrict__ HFc,
                                              const float* __restrict__ Zc,
                                              const short* __restrict__ Wt,
                                              const float* __restrict__ Bc,
                                              const float* __restrict__ outb,
                                              const short* __restrict__ zb,
                                              float* __restrict__ out) {
  const int t = threadIdx.x, wv = t >> 6, l = t & 63;
  const int tile = blockIdx.x, b = tile >> 11, p0 = (tile & 2047) << 3;
  const int m0 = p0 << 3, k0 = m0 >> 14, poff = m0 & (HWp - 1);

  __shared__ float AO[8 * 68];

  const int am = l & 15, kg = l >> 4;
  const int row0 = wv << 4;
  const int c0a = kg * 8;
  const int rowK = row0 + am;
  const int pq = p0 + 2 * wv + (am >> 3);

  const short* Wq = Wt + 3 * 64 * WSTRIDE;
  const short* Wk = Wt + 4 * 64 * WSTRIDE;
  const short* Wv = Wt + 5 * 64 * WSTRIDE;
  const short* Wo = Wt + 6 * 64 * WSTRIDE;
  const float* BQ = Bc + 192;
  const float* BK = Bc + 256;
  const float* BV = Bc + 320;

  const float* baseKc = HFc + ((size_t)(b * KC + k0) * CH) * HWp + poff;
  const float* baseZc = Zc + ((size_t)(b * KC + k0) * CH) * HWp + poff;
  const float* baseQ = HFs + (size_t)b * CH * HWp;
  const short* zK = zb + ((size_t)(b * HWp + poff + rowK)) * 64;
  const short* zQ = zb + ((size_t)(b * HWp + pq)) * 64;
  const float inv127 = 1.f / 127.f;

  // ---- prefetch all global A-data ----
  float rK[16], rQ[16], rV[16];
  bf16x8 zKf[2], zQf[2];
#pragma unroll
  for (int ks = 0; ks < 2; ++ks)
#pragma unroll
    for (int j = 0; j < 8; ++j)
      rK[ks * 8 + j] = baseKc[(size_t)(ks * 32 + c0a + j) * HWp + rowK];
#pragma unroll
  for (int ks = 0; ks < 2; ++ks)
#pragma unroll
    for (int j = 0; j < 8; ++j)
      rQ[ks * 8 + j] = baseQ[(size_t)(ks * 32 + c0a + j) * HWp + pq];
#pragma unroll
  for (int ks = 0; ks < 2; ++ks)
#pragma unroll
    for (int j = 0; j < 8; ++j)
      rV[ks * 8 + j] = baseZc[(size_t)(ks * 32 + c0a + j) * HWp + rowK];
#pragma unroll
  for (int i = 0; i < 2; ++i) {
    zKf[i] = *(const bf16x8*)(zK + i * 32 + c0a);
    zQf[i] = *(const bf16x8*)(zQ + i * 32 + c0a);
  }

  // ---- K & Q GEMMs over K=128 (+coords at 128/129) ----
  const int pqd = p0 + 2 * wv + (kg >> 1);
  const float qi = (float)(pqd >> 7) * inv127, qj = (float)(pqd & 127) * inv127;
  f32x4 kacc[4], qacc[4];
#pragma unroll
  for (int ct = 0; ct < 4; ++ct) {
    int col = ct * 16 + am;
    float bk = BK[col], wi = bf2f(Wk[col * WSTRIDE + 128]), wj = bf2f(Wk[col * WSTRIDE + 129]);
#pragma unroll
    for (int r = 0; r < 4; ++r) {
      int pp = poff + row0 + kg * 4 + r;
      kacc[ct][r] = bk + (float)(pp >> 7) * inv127 * wi + (float)(pp & 127) * inv127 * wj;
    }
    float bq = BQ[col] + qi * bf2f(Wq[col * WSTRIDE + 128]) + qj * bf2f(Wq[col * WSTRIDE + 129]);
#pragma unroll
    for (int r = 0; r < 4; ++r) qacc[ct][r] = bq;
  }
#pragma unroll
  for (int ks = 0; ks < 4; ++ks) {
    int c0 = ks * 32 + c0a;
    bf16x8 aK = (ks < 2) ? cvt8(rK + ks * 8) : zKf[ks - 2];
    bf16x8 aQ = (ks < 2) ? cvt8(rQ + ks * 8) : zQf[ks - 2];
#pragma unroll
    for (int ct = 0; ct < 4; ++ct) {
      kacc[ct] = MFMA(aK, ldB(Wk, ct * 16 + am, c0), kacc[ct]);
      qacc[ct] = MFMA(aQ, ldB(Wq, ct * 16 + am, c0), qacc[ct]);
    }
  }

  // ---- scores ----
  float sc[4][4];
#pragma unroll
  for (int ct = 0; ct < 4; ++ct)
#pragma unroll
    for (int r = 0; r < 4; ++r) sc[ct][r] = kacc[ct][r] * qacc[ct][0];
#pragma unroll
  for (int m = 1; m < 16; m <<= 1)
#pragma unroll
    for (int ct = 0; ct < 4; ++ct)
#pragma unroll
      for (int r = 0; r < 4; ++r) sc[ct][r] += __shfl_xor(sc[ct][r], m);

  float aw[4][4];
#pragma unroll
  for (int ct = 0; ct < 4; ++ct) {
    float so[4];
#pragma unroll
    for (int r = 0; r < 4; ++r) { sc[ct][r] *= 0.25f; so[r] = __shfl_xor(sc[ct][r], 16); }
    float mx = fmaxf(fmaxf(fmaxf(sc[ct][0], sc[ct][1]), fmaxf(sc[ct][2], sc[ct][3])),
                     fmaxf(fmaxf(so[0], so[1]), fmaxf(so[2], so[3])));
    float e[4], s = 0.f;
#pragma unroll
    for (int r = 0; r < 4; ++r) { e[r] = __expf(sc[ct][r] - mx); s += e[r]; }
#pragma unroll
    for (int r = 0; r < 4; ++r) s += __expf(so[r] - mx);
    float inv = 1.0f / s;
#pragma unroll
    for (int r = 0; r < 4; ++r) aw[ct][r] = e[r] * inv;
  }

  // ---- V GEMM: [Zc | z] ----
  f32x4 vacc[4];
#pragma unroll
  for (int ct = 0; ct < 4; ++ct) {
    float bv = BV[ct * 16 + am];
#pragma unroll
    for (int r = 0; r < 4; ++r) vacc[ct][r] = bv;
  }
#pragma unroll
  for (int ks = 0; ks < 4; ++ks) {
    int c0 = ks * 32 + c0a;
    bf16x8 aV = (ks < 2) ? cvt8(rV + ks * 8) : zKf[ks - 2];
#pragma unroll
    for (int ct = 0; ct < 4; ++ct) vacc[ct] = MFMA(aV, ldB(Wv, ct * 16 + am, c0), vacc[ct]);
  }

  // ---- attn @ V ----
#pragma unroll
  for (int ct = 0; ct < 4; ++ct) {
    float po = aw[ct][0] * vacc[ct][0] + aw[ct][1] * vacc[ct][1] +
               aw[ct][2] * vacc[ct][2] + aw[ct][3] * vacc[ct][3];
    po += __shfl_xor(po, 16);
    if ((kg & 1) == 0) AO[(2 * wv + (kg >> 1)) * 68 + ct * 16 + am] = po;
  }
  __syncthreads();

  // ---- out-projection -> d_out [B,E,H,W] fp32 ----
  {
    int colo = wv * 16 + am;
    f32x4 oacc;
    float bo = outb[colo];
#pragma unroll
    for (int r = 0; r < 4; ++r) oacc[r] = bo;
#pragma unroll
    for (int ks = 0; ks < 2; ++ks) {
      int c0 = ks * 32 + c0a;
      bf16x8 a;
#pragma unroll
      for (int j = 0; j < 8; ++j) a[j] = f2bf(AO[(am & 7) * 68 + c0 + j]);
      oacc = MFMA(a, ldB(Wo, colo, c0), oacc);
    }
#pragma unroll
    for (int r = 0; r < 4; ++r) {
      int m = kg * 4 + r;
      if (m < 8) out[((size_t)(b * 64 + colo)) * HWp + p0 + m] = oacc[r];
    }
  }
}

extern "C" void kernel_launch(void* const* d_in, const int* in_sizes, int n_in,
                              void* d_out, int out_size, void* d_ws, size_t ws_size,
                              hipStream_t stream) {
  const float* HFs = (const float*)d_in[0];
  const float* HFc = (const float*)d_in[1];
  const float* Zc = (const float*)d_in[2];
  const float* q1w = (const float*)d_in[3];  const float* q1b = (const float*)d_in[4];
  const float* k1w = (const float*)d_in[5];  const float* k1b = (const float*)d_in[6];
  const float* v1w = (const float*)d_in[7];  const float* v1b = (const float*)d_in[8];
  const float* q2w = (const float*)d_in[9];  const float* q2b = (const float*)d_in[10];
  const float* k2w = (const float*)d_in[11]; const float* k2b = (const float*)d_in[12];
  const float* v2w = (const float*)d_in[13]; const float* v2b = (const float*)d_in[14];
  const float* ipw = (const float*)d_in[15]; const float* ipb = (const float*)d_in[16];
  const float* ow = (const float*)d_in[17];  const float* ob = (const float*)d_in[18];

  short* Wt = (short*)d_ws;                    // 7 x 64 x 136 bf16
  float* Bc = (float*)((char*)d_ws + 121856);  // 6 x 64 fp32
  short* zb = (short*)((char*)d_ws + 131072);  // B*HW*64 bf16
  float* out = (float*)d_out;

  dim3 gsetup(33, 7);
  setup_weights<<<gsetup, 256, 0, stream>>>(q1w, q1b, k1w, k1b, v1w, v1b,
                                            q2w, q2b, k2w, k2b, v2w, v2b,
                                            ipw, ipb, ow, Wt, Bc);
  stage1<<<8192, 256, 0, stream>>>(HFs, HFc, Zc, Wt, Bc, ob, zb);
  stage2<<<8192, 256, 0, stream>>>(HFs, HFc, Zc, Wt, Bc, ob, zb, out);
}